// Round 4
// baseline (54.529 us; speedup 1.0000x reference)
//
#include <hip/hip_runtime.h>

// Problem constants (from reference): V=50000, F=100000, H=W=256, K=1, B=4, J=256
#define HH    256
#define WW    256
#define NPIX  (HH * WW)          // 65536
#define BB    4
#define JJ    256

// Output layout (concatenated flat, fp32):
//   colors  : (B,H,W,3)  base 0            size 786432
//   diffuse : (B,H,W,3)  base 786432       size 786432
//   texels  : (1,H,W,3)  base 1572864      size 196608
//   normals : (B,H,W,3)  base 1769472      size 786432

// Grid: 2048 blocks x 256 threads.
//   b    = blockIdx.x >> 9          (batch, block-uniform)
//   pix  = (blockIdx.x & 511)*128 + (tid & 127)
//   half = tid >> 7                 (wave-uniform light-range selector)
// Each thread accumulates 128 lights; halves merge through LDS.
__global__ __launch_bounds__(256) void shade_kernel(
    const int*   __restrict__ p2f,    // (1,H,W,1) int32
    const float* __restrict__ bary,   // (1,H,W,1,3)
    const int*   __restrict__ faces,  // (F,3)
    const float* __restrict__ vnorm,  // (V,3)
    const float* __restrict__ dirs,   // (B,J,3)
    const float* __restrict__ env,    // (B,J,3)
    const float* __restrict__ tex,    // (1,H,W,3)
    float*       __restrict__ out)
{
    const int b    = blockIdx.x >> 9;                       // batch (block-uniform)
    const int half = threadIdx.x >> 7;                      // wave-uniform
    const int i    = threadIdx.x & 127;
    const int p    = ((blockIdx.x & 511) << 7) | i;         // pixel 0..65535

    // ---- per-pixel normal (gather + barycentric blend + normalize) ----
    const int f  = p2f[p];
    const int v0 = faces[3*f + 0];
    const int v1 = faces[3*f + 1];
    const int v2 = faces[3*f + 2];
    const float b0 = bary[3*p + 0];
    const float b1 = bary[3*p + 1];
    const float b2 = bary[3*p + 2];

    float nx = b0 * vnorm[3*v0 + 0] + b1 * vnorm[3*v1 + 0] + b2 * vnorm[3*v2 + 0];
    float ny = b0 * vnorm[3*v0 + 1] + b1 * vnorm[3*v1 + 1] + b2 * vnorm[3*v2 + 1];
    float nz = b0 * vnorm[3*v0 + 2] + b1 * vnorm[3*v1 + 2] + b2 * vnorm[3*v2 + 2];

    const float nrm = fmaxf(sqrtf(nx*nx + ny*ny + nz*nz), 1e-6f);
    const float inv = 1.0f / nrm;
    nx *= inv; ny *= inv; nz *= inv;

    // ---- accumulate 128 lights (wave-uniform scalar loads) ----
    float ar = 0.f, ag = 0.f, ab = 0.f;
    const float* __restrict__ dp = dirs + b * (JJ * 3) + half * (128 * 3);
    const float* __restrict__ ep = env  + b * (JJ * 3) + half * (128 * 3);

    #pragma unroll 8
    for (int j = 0; j < 128; ++j) {
        const float dx = dp[3*j + 0];
        const float dy = dp[3*j + 1];
        const float dz = dp[3*j + 2];
        float w = fmaf(nz, dz, fmaf(ny, dy, nx * dx));
        w = fminf(fmaxf(w, 0.f), 1.f);          // -> v_med3_f32
        ar = fmaf(ep[3*j + 0], w, ar);
        ag = fmaf(ep[3*j + 1], w, ag);
        ab = fmaf(ep[3*j + 2], w, ab);
    }

    // ---- merge halves through LDS (stride-3 floats: conflict-free) ----
    __shared__ float lds[128 * 3];
    if (half == 1) {
        lds[3*i + 0] = ar;
        lds[3*i + 1] = ag;
        lds[3*i + 2] = ab;
    }
    __syncthreads();

    if (half == 0) {
        ar += lds[3*i + 0];
        ag += lds[3*i + 1];
        ab += lds[3*i + 2];

        const float tr = tex[3*p + 0];
        const float tg = tex[3*p + 1];
        const float tb = tex[3*p + 2];

        const int o = 3 * (b * NPIX + p);

        // colors = diffuse * texels
        out[o + 0] = ar * tr;
        out[o + 1] = ag * tg;
        out[o + 2] = ab * tb;

        // diffuse
        float* __restrict__ dif = out + 3 * BB * NPIX;
        dif[o + 0] = ar;
        dif[o + 1] = ag;
        dif[o + 2] = ab;

        // normals (broadcast of pixel normal over B)
        float* __restrict__ nor = out + 3 * BB * NPIX * 2 + 3 * NPIX;
        nor[o + 0] = nx;
        nor[o + 1] = ny;
        nor[o + 2] = nz;

        // texels passthrough (batch-0 blocks only)
        if (b == 0) {
            float* __restrict__ tx = out + 3 * BB * NPIX * 2;
            tx[3*p + 0] = tr;
            tx[3*p + 1] = tg;
            tx[3*p + 2] = tb;
        }
    }
}

extern "C" void kernel_launch(void* const* d_in, const int* in_sizes, int n_in,
                              void* d_out, int out_size, void* d_ws, size_t ws_size,
                              hipStream_t stream) {
    const int*   p2f   = (const int*)  d_in[0];
    const float* bary  = (const float*)d_in[1];
    const int*   faces = (const int*)  d_in[2];
    // d_in[3] = verts (unused by the reference computation)
    const float* vnorm = (const float*)d_in[4];
    const float* dirs  = (const float*)d_in[5];
    const float* env   = (const float*)d_in[6];
    const float* tex   = (const float*)d_in[7];
    float* out = (float*)d_out;

    const int grid = BB * (NPIX / 128);   // 4 * 512 = 2048 blocks
    shade_kernel<<<grid, 256, 0, stream>>>(
        p2f, bary, faces, vnorm, dirs, env, tex, out);
}

// Round 5
// 24.420 us; speedup vs baseline: 2.2329x; 2.2329x over previous
//
#include <hip/hip_runtime.h>

// Problem constants: V=50000, F=100000, H=W=256, K=1, B=4, J=256
#define HH    256
#define WW    256
#define NPIX  (HH * WW)          // 65536
#define BB    4
#define JJ    256

// Output layout (concatenated flat, fp32):
//   colors  : (B,H,W,3)  base 0
//   diffuse : (B,H,W,3)  base 786432
//   texels  : (1,H,W,3)  base 1572864
//   normals : (B,H,W,3)  base 1769472

// Grid: 1024 blocks x 256 threads.
//   b  = blockIdx.x >> 8   (batch, block-uniform)
//   pb = blockIdx.x & 255  (pixel block: 256 pixels)
// Within a block: wave w (= tid>>6) handles light quarter jq = readfirstlane(w)
// (forced SGPR -> provably uniform -> s_load for lights; round-4 lesson).
// Each thread owns 4 pixels (k*64 + lane), giving 28 VALU ops per 6 scalar
// dwords in the light loop. Partials merged via 12 KB LDS.
__global__ __launch_bounds__(256) void shade_kernel(
    const int*   __restrict__ p2f,    // (1,H,W,1) int32
    const float* __restrict__ bary,   // (1,H,W,1,3)
    const int*   __restrict__ faces,  // (F,3)
    const float* __restrict__ vnorm,  // (V,3)
    const float* __restrict__ dirs,   // (B,J,3)
    const float* __restrict__ env,    // (B,J,3)
    const float* __restrict__ tex,    // (1,H,W,3)
    float*       __restrict__ out)
{
    const int b   = blockIdx.x >> 8;                 // batch (block-uniform)
    const int pb  = blockIdx.x & 255;                // pixel block
    const int i   = threadIdx.x & 63;                // lane
    const int jq  = __builtin_amdgcn_readfirstlane(threadIdx.x >> 6); // SGPR

    const int pbase = pb << 8;                       // first pixel of block

    // ---- Phase A1: gather + normalize 4 pixel normals ----
    float nX[4], nY[4], nZ[4];
    #pragma unroll
    for (int k = 0; k < 4; ++k) {
        const int p = pbase + (k << 6) + i;
        const int f  = p2f[p];
        const int v0 = faces[3*f + 0];
        const int v1 = faces[3*f + 1];
        const int v2 = faces[3*f + 2];
        const float b0 = bary[3*p + 0];
        const float b1 = bary[3*p + 1];
        const float b2 = bary[3*p + 2];
        float nx = b0*vnorm[3*v0+0] + b1*vnorm[3*v1+0] + b2*vnorm[3*v2+0];
        float ny = b0*vnorm[3*v0+1] + b1*vnorm[3*v1+1] + b2*vnorm[3*v2+1];
        float nz = b0*vnorm[3*v0+2] + b1*vnorm[3*v1+2] + b2*vnorm[3*v2+2];
        const float inv = 1.0f / fmaxf(sqrtf(nx*nx + ny*ny + nz*nz), 1e-6f);
        nX[k] = nx * inv; nY[k] = ny * inv; nZ[k] = nz * inv;
    }

    // ---- Phase A2: accumulate 64 lights (wave-uniform scalar loads) ----
    float aR[4] = {0,0,0,0}, aG[4] = {0,0,0,0}, aB[4] = {0,0,0,0};
    const float* __restrict__ dp = dirs + b * (JJ*3) + jq * (64*3);
    const float* __restrict__ ep = env  + b * (JJ*3) + jq * (64*3);

    #pragma unroll 8
    for (int j = 0; j < 64; ++j) {
        const float dx = dp[3*j + 0];
        const float dy = dp[3*j + 1];
        const float dz = dp[3*j + 2];
        const float er = ep[3*j + 0];
        const float eg = ep[3*j + 1];
        const float eb = ep[3*j + 2];
        #pragma unroll
        for (int k = 0; k < 4; ++k) {
            float w = fmaf(nZ[k], dz, fmaf(nY[k], dy, nX[k] * dx));
            w = fminf(fmaxf(w, 0.f), 1.f);       // v_med3_f32
            aR[k] = fmaf(er, w, aR[k]);
            aG[k] = fmaf(eg, w, aG[k]);
            aB[k] = fmaf(eb, w, aB[k]);
        }
    }

    // ---- Phase B: partials -> LDS; jq0 wave also writes normals/texels ----
    __shared__ float part[4][256][3];                // 12 KB
    const int wv = threadIdx.x >> 6;                 // LDS slot (vector ok)
    #pragma unroll
    for (int k = 0; k < 4; ++k) {
        const int s = (k << 6) + i;
        part[wv][s][0] = aR[k];
        part[wv][s][1] = aG[k];
        part[wv][s][2] = aB[k];
    }
    if (wv == 0) {
        float* __restrict__ nor = out + 3 * BB * NPIX * 2 + 3 * NPIX;
        #pragma unroll
        for (int k = 0; k < 4; ++k) {
            const int p = pbase + (k << 6) + i;
            const int o = 3 * (b * NPIX + p);
            nor[o + 0] = nX[k];
            nor[o + 1] = nY[k];
            nor[o + 2] = nZ[k];
        }
        if (b == 0) {
            float* __restrict__ tx = out + 3 * BB * NPIX * 2;
            #pragma unroll
            for (int k = 0; k < 4; ++k) {
                const int p = pbase + (k << 6) + i;
                tx[3*p + 0] = tex[3*p + 0];
                tx[3*p + 1] = tex[3*p + 1];
                tx[3*p + 2] = tex[3*p + 2];
            }
        }
    }
    __syncthreads();

    // ---- Phase C: every thread sums one pixel across the 4 quarters ----
    {
        const int s = threadIdx.x;                   // local pixel slot
        const int p = pbase + s;
        const float sr = part[0][s][0] + part[1][s][0] + part[2][s][0] + part[3][s][0];
        const float sg = part[0][s][1] + part[1][s][1] + part[2][s][1] + part[3][s][1];
        const float sb = part[0][s][2] + part[1][s][2] + part[2][s][2] + part[3][s][2];

        const float tr = tex[3*p + 0];
        const float tg = tex[3*p + 1];
        const float tb = tex[3*p + 2];

        const int o = 3 * (b * NPIX + p);
        out[o + 0] = sr * tr;
        out[o + 1] = sg * tg;
        out[o + 2] = sb * tb;

        float* __restrict__ dif = out + 3 * BB * NPIX;
        dif[o + 0] = sr;
        dif[o + 1] = sg;
        dif[o + 2] = sb;
    }
}

extern "C" void kernel_launch(void* const* d_in, const int* in_sizes, int n_in,
                              void* d_out, int out_size, void* d_ws, size_t ws_size,
                              hipStream_t stream) {
    const int*   p2f   = (const int*)  d_in[0];
    const float* bary  = (const float*)d_in[1];
    const int*   faces = (const int*)  d_in[2];
    // d_in[3] = verts (unused)
    const float* vnorm = (const float*)d_in[4];
    const float* dirs  = (const float*)d_in[5];
    const float* env   = (const float*)d_in[6];
    const float* tex   = (const float*)d_in[7];
    float* out = (float*)d_out;

    const int grid = BB * (NPIX / 256);   // 4 * 256 = 1024 blocks
    shade_kernel<<<grid, 256, 0, stream>>>(
        p2f, bary, faces, vnorm, dirs, env, tex, out);
}

// Round 6
// 19.722 us; speedup vs baseline: 2.7649x; 1.2382x over previous
//
#include <hip/hip_runtime.h>

// Problem constants: V=50000, F=100000, H=W=256, K=1, B=4, J=256
#define NPIX  65536
#define BB    4
#define JJ    256

// Output layout (concatenated flat, fp32):
//   colors  : (B,H,W,3)  base 0
//   diffuse : (B,H,W,3)  base 786432
//   texels  : (1,H,W,3)  base 1572864
//   normals : (B,H,W,3)  base 1769472

struct F3 { float x, y, z; };
struct I3 { int x, y, z; };

// Grid: 2048 blocks x 256 threads (8192 waves = 32/CU, 100% occupancy).
//   b  = blockIdx.x >> 9   (batch, block-uniform)
//   pb = blockIdx.x & 511  (128-pixel block)
// Phase A1: threads 0..127 gather+normalize the block's 128 normals -> LDS
//           (gather happens ONCE per pixel, not once per wave).
// Phase A2: wave w handles light quarter jq=readfirstlane(w) (SGPR -> s_load),
//           each thread 2 pixels x 64 lights.
// Phase B/C: partials merged via LDS, 128 threads write colors/diffuse.
__global__ __launch_bounds__(256, 8) void shade_kernel(
    const int*   __restrict__ p2f,    // (1,H,W,1) int32
    const float* __restrict__ bary,   // (1,H,W,1,3)
    const int*   __restrict__ faces,  // (F,3)
    const float* __restrict__ vnorm,  // (V,3)
    const float* __restrict__ dirs,   // (B,J,3)
    const float* __restrict__ env,    // (B,J,3)
    const float* __restrict__ tex,    // (1,H,W,3)
    float*       __restrict__ out)
{
    const int b     = blockIdx.x >> 9;                 // batch (block-uniform)
    const int pbase = (blockIdx.x & 511) << 7;         // first pixel of block
    const int t     = threadIdx.x;
    const int i     = t & 63;                          // lane
    const int jq    = __builtin_amdgcn_readfirstlane(t >> 6);  // light quarter (SGPR)

    __shared__ float nlds[128][3];                     // 1.5 KB normals
    __shared__ float part[4][128][3];                  // 6 KB partials

    const F3* __restrict__ bary3  = (const F3*)bary;
    const I3* __restrict__ faces3 = (const I3*)faces;
    const F3* __restrict__ vn3    = (const F3*)vnorm;
    const F3* __restrict__ tex3   = (const F3*)tex;

    // ---- Phase A1: gather + normalize (once per pixel) ----
    if (t < 128) {
        const int p = pbase + t;
        const int f = p2f[p];
        const I3 vv = faces3[f];                       // dwordx3 scattered
        const F3 bc = bary3[p];                        // dwordx3 coalesced
        const F3 a0 = vn3[vv.x];
        const F3 a1 = vn3[vv.y];
        const F3 a2 = vn3[vv.z];
        float nx = bc.x*a0.x + bc.y*a1.x + bc.z*a2.x;
        float ny = bc.x*a0.y + bc.y*a1.y + bc.z*a2.y;
        float nz = bc.x*a0.z + bc.y*a1.z + bc.z*a2.z;
        const float inv = 1.0f / fmaxf(sqrtf(nx*nx + ny*ny + nz*nz), 1e-6f);
        nx *= inv; ny *= inv; nz *= inv;
        nlds[t][0] = nx; nlds[t][1] = ny; nlds[t][2] = nz;

        // normals output (this block's batch copy)
        float* __restrict__ nor = out + (3*BB*NPIX*2 + 3*NPIX);
        const int o = 3*(b*NPIX + p);
        nor[o+0] = nx; nor[o+1] = ny; nor[o+2] = nz;

        // texels passthrough (batch-0 blocks cover all pixels)
        if (b == 0) {
            const F3 tv = tex3[p];
            float* __restrict__ tx = out + 3*BB*NPIX*2;
            tx[3*p+0] = tv.x; tx[3*p+1] = tv.y; tx[3*p+2] = tv.z;
        }
    }
    __syncthreads();

    // ---- Phase A2: 2 pixels/thread, 64 lights (scalar-loaded) ----
    const float n0x = nlds[i][0],    n0y = nlds[i][1],    n0z = nlds[i][2];
    const float n1x = nlds[64+i][0], n1y = nlds[64+i][1], n1z = nlds[64+i][2];

    float a0r=0.f, a0g=0.f, a0b=0.f, a1r=0.f, a1g=0.f, a1b=0.f;
    const float* __restrict__ dp = dirs + b*(JJ*3) + jq*(64*3);
    const float* __restrict__ ep = env  + b*(JJ*3) + jq*(64*3);

    #pragma unroll 8
    for (int j = 0; j < 64; ++j) {
        const float dx = dp[3*j+0], dy = dp[3*j+1], dz = dp[3*j+2];
        const float er = ep[3*j+0], eg = ep[3*j+1], eb = ep[3*j+2];
        float w0 = fmaf(n0z, dz, fmaf(n0y, dy, n0x*dx));
        float w1 = fmaf(n1z, dz, fmaf(n1y, dy, n1x*dx));
        w0 = fminf(fmaxf(w0, 0.f), 1.f);               // v_med3_f32
        w1 = fminf(fmaxf(w1, 0.f), 1.f);
        a0r = fmaf(er, w0, a0r); a0g = fmaf(eg, w0, a0g); a0b = fmaf(eb, w0, a0b);
        a1r = fmaf(er, w1, a1r); a1g = fmaf(eg, w1, a1g); a1b = fmaf(eb, w1, a1b);
    }

    // ---- Phase B: partials -> LDS ----
    const int w = t >> 6;
    part[w][i][0]    = a0r; part[w][i][1]    = a0g; part[w][i][2]    = a0b;
    part[w][64+i][0] = a1r; part[w][64+i][1] = a1g; part[w][64+i][2] = a1b;
    __syncthreads();

    // ---- Phase C: reduce quarters, write colors + diffuse ----
    if (t < 128) {
        const int p = pbase + t;
        const float sr = part[0][t][0]+part[1][t][0]+part[2][t][0]+part[3][t][0];
        const float sg = part[0][t][1]+part[1][t][1]+part[2][t][1]+part[3][t][1];
        const float sb = part[0][t][2]+part[1][t][2]+part[2][t][2]+part[3][t][2];

        const F3 tv = tex3[p];
        const int o = 3*(b*NPIX + p);
        out[o+0] = sr*tv.x; out[o+1] = sg*tv.y; out[o+2] = sb*tv.z;

        float* __restrict__ dif = out + 3*BB*NPIX;
        dif[o+0] = sr; dif[o+1] = sg; dif[o+2] = sb;
    }
}

extern "C" void kernel_launch(void* const* d_in, const int* in_sizes, int n_in,
                              void* d_out, int out_size, void* d_ws, size_t ws_size,
                              hipStream_t stream) {
    const int*   p2f   = (const int*)  d_in[0];
    const float* bary  = (const float*)d_in[1];
    const int*   faces = (const int*)  d_in[2];
    // d_in[3] = verts (unused)
    const float* vnorm = (const float*)d_in[4];
    const float* dirs  = (const float*)d_in[5];
    const float* env   = (const float*)d_in[6];
    const float* tex   = (const float*)d_in[7];
    float* out = (float*)d_out;

    const int grid = BB * (NPIX / 128);   // 4 * 512 = 2048 blocks
    shade_kernel<<<grid, 256, 0, stream>>>(
        p2f, bary, faces, vnorm, dirs, env, tex, out);
}